// Round 6
// baseline (394.145 us; speedup 1.0000x reference)
//
#include <hip/hip_runtime.h>
#include <math.h>

#define DI __device__ __forceinline__

typedef __attribute__((ext_vector_type(4))) float  f32x4;
typedef __attribute__((ext_vector_type(4))) short  s16x4;
typedef __attribute__((ext_vector_type(8))) short  s16x8;
typedef __attribute__((ext_vector_type(4))) float  ffrag;
typedef s16x8 bfrag;

constexpr int NT = 8192;   // B*S tokens
constexpr int D  = 4096;
constexpr int NE = 8;      // experts
constexpr int KE = 128;    // E * R
constexpr int KX = D + KE; // 4224 extended K

DI short f2bf(float f) {
  unsigned u = __builtin_bit_cast(unsigned, f);
  u += 0x7FFFu + ((u >> 16) & 1u);   // RNE
  return (short)(u >> 16);
}
DI float bf2f(short h) {
  unsigned u = ((unsigned)(unsigned short)h) << 16;
  return __builtin_bit_cast(float, u);
}

#define GLOAD16(gp, lp)                                                        \
  __builtin_amdgcn_global_load_lds(                                            \
      (const __attribute__((address_space(1))) void*)(gp),                     \
      (__attribute__((address_space(3))) void*)(lp), 16, 0, 0)

// ---------------------------------------------------------------- detect
__global__ void moe_k_detect(const unsigned* __restrict__ x, int* __restrict__ flag) {
  int l = threadIdx.x;
  int cnt = 0;
  for (int i = l; i < 2048; i += 64) {
    unsigned e = (x[i] >> 23) & 0xFFu;
    cnt += (e >= 110u && e <= 140u) ? 1 : 0;
  }
#pragma unroll
  for (int o = 32; o; o >>= 1) cnt += __shfl_xor(cnt, o);
  if (l == 0) flag[0] = (cnt > 1024) ? 0 : 1;
}

// ---------------------------------------------------------------- prep + xrouter (fused)
__global__ __launch_bounds__(256)
void moe_k_prep_xr(const void* __restrict__ wp, const void* __restrict__ lAp,
                   const void* __restrict__ lBp, const void* __restrict__ xp,
                   const void* __restrict__ rp, const int* __restrict__ flag,
                   short* __restrict__ Wb, short* __restrict__ Abt,
                   short* __restrict__ Xb, float* __restrict__ wdense) {
  const bool bf = flag[0] != 0;
  int b = blockIdx.x, t = threadIdx.x;
  if (b < 8192) {
    int tid = b * 256 + t;
    int row = tid >> 9;
    int col = (tid & 511) << 3;
    s16x8 o;
    if (!bf) {
      const float* Wf = (const float*)wp;
      f32x4 v0 = *(const f32x4*)&Wf[(size_t)row * 4096 + col];
      f32x4 v1 = *(const f32x4*)&Wf[(size_t)row * 4096 + col + 4];
      o[0] = f2bf(v0[0]); o[1] = f2bf(v0[1]); o[2] = f2bf(v0[2]); o[3] = f2bf(v0[3]);
      o[4] = f2bf(v1[0]); o[5] = f2bf(v1[1]); o[6] = f2bf(v1[2]); o[7] = f2bf(v1[3]);
    } else {
      o = *(const s16x8*)&((const short*)wp)[(size_t)row * 4096 + col];
    }
    *(s16x8*)&Wb[(size_t)row * KX + col] = o;
  } else if (b < 8208) {
    int d = (b - 8192) * 256 + t;
    for (int j0 = 0; j0 < KE; j0 += 8) {
      s16x8 o;
#pragma unroll
      for (int i = 0; i < 8; ++i) {
        float v = bf ? bf2f(((const short*)lBp)[(size_t)(j0 + i) * 4096 + d])
                     : ((const float*)lBp)[(size_t)(j0 + i) * 4096 + d];
        o[i] = f2bf(2.0f * v);
      }
      *(s16x8*)&Wb[(size_t)d * KX + 4096 + j0] = o;
    }
  } else if (b < 8336) {
    int j = b - 8208;
    int e = j >> 4, r = j & 15;
    for (int d = t; d < 4096; d += 256) {
      size_t src = ((size_t)e * 4096 + d) * 16 + r;
      short v = bf ? ((const short*)lAp)[src] : f2bf(((const float*)lAp)[src]);
      Abt[(size_t)j * 4096 + d] = v;
    }
  } else {
    int wv = t >> 6, l = t & 63;
    int n = (b - 8336) * 4 + wv;
    float acc[NE];
#pragma unroll
    for (int e = 0; e < NE; ++e) acc[e] = 0.f;
    const float* xf = (const float*)xp;
    const short* xh = (const short*)xp;
    const float* rf = (const float*)rp;
    const short* rh = (const short*)rp;
    for (int it = 0; it < 16; ++it) {
      int d = it * 256 + l * 4;
      float x0, x1, x2, x3;
      s16x4 xo;
      if (!bf) {
        f32x4 v = *(const f32x4*)&xf[(size_t)n * D + d];
        x0 = v[0]; x1 = v[1]; x2 = v[2]; x3 = v[3];
        xo[0] = f2bf(x0); xo[1] = f2bf(x1); xo[2] = f2bf(x2); xo[3] = f2bf(x3);
      } else {
        xo = *(const s16x4*)&xh[(size_t)n * D + d];
        x0 = bf2f(xo[0]); x1 = bf2f(xo[1]); x2 = bf2f(xo[2]); x3 = bf2f(xo[3]);
      }
      *(s16x4*)&Xb[(size_t)n * KX + d] = xo;
#pragma unroll
      for (int e = 0; e < NE; ++e) {
        if (!bf) {
          f32x4 w = *(const f32x4*)&rf[(size_t)e * D + d];
          acc[e] += x0 * w[0] + x1 * w[1] + x2 * w[2] + x3 * w[3];
        } else {
          s16x4 w = *(const s16x4*)&rh[(size_t)e * D + d];
          acc[e] += x0 * bf2f(w[0]) + x1 * bf2f(w[1]) + x2 * bf2f(w[2]) + x3 * bf2f(w[3]);
        }
      }
    }
#pragma unroll
    for (int e = 0; e < NE; ++e) {
#pragma unroll
      for (int o = 32; o; o >>= 1) acc[e] += __shfl_xor(acc[e], o);
    }
    float m = acc[0];
#pragma unroll
    for (int e = 1; e < NE; ++e) m = fmaxf(m, acc[e]);
    float p[NE];
#pragma unroll
    for (int e = 0; e < NE; ++e) p[e] = __expf(acc[e] - m);
    int i1 = 0; float v1 = p[0];
#pragma unroll
    for (int e = 1; e < NE; ++e) { if (p[e] > v1) { v1 = p[e]; i1 = e; } }
    int i2 = 0; float v2 = -1.f;
#pragma unroll
    for (int e = 0; e < NE; ++e) { if (e != i1 && p[e] > v2) { v2 = p[e]; i2 = e; } }
    float inv = 1.f / (v1 + v2);
    if (l < NE) {
      float w = (l == i1) ? v1 * inv : ((l == i2) ? v2 * inv : 0.f);
      wdense[(size_t)n * NE + l] = w;
    }
  }
}

// ---------------------------------------------------------------- mid GEMM v2 (unchanged)
__global__ __launch_bounds__(256)
void moe_k_mid2(const short* __restrict__ Xb, const short* __restrict__ Abt,
                const float* __restrict__ wdense, short* __restrict__ XbW) {
  __shared__ __align__(16) short LDS[16384];
  const int t = threadIdx.x, l = t & 63, wv = t >> 6;
  const int wr = wv >> 1, wc = wv & 1;
  const int lr = l & 15, kq = l >> 4;
  const int m0 = (blockIdx.x >> 1) * 64;
  const int j0 = (blockIdx.x & 1) * 64;

  ffrag acc[2][2];
#pragma unroll
  for (int i = 0; i < 2; ++i)
#pragma unroll
    for (int j = 0; j < 2; ++j)
#pragma unroll
      for (int q = 0; q < 4; ++q) acc[i][j][q] = 0.f;

  const int srow = t >> 2, sslot = t & 3;
#define MSTAGE(kt_)                                                            \
  do {                                                                         \
    int _k0 = (kt_) * 32, _b = ((kt_) & 3) * 4096;                             \
    GLOAD16(&Xb[(size_t)(m0 + srow) * KX + _k0 + sslot * 8], &LDS[_b + t * 8]);\
    GLOAD16(&Abt[(size_t)(j0 + srow) * 4096 + _k0 + sslot * 8],                \
            &LDS[_b + 2048 + t * 8]);                                          \
  } while (0)

  MSTAGE(0); MSTAGE(1); MSTAGE(2);
  constexpr int NKT = 128;

  for (int kt = 0; kt < NKT; ++kt) {
    if (kt + 2 < NKT)      asm volatile("s_waitcnt vmcnt(4)" ::: "memory");
    else if (kt + 1 < NKT) asm volatile("s_waitcnt vmcnt(2)" ::: "memory");
    else                   asm volatile("s_waitcnt vmcnt(0)" ::: "memory");
    __builtin_amdgcn_s_barrier();
    __builtin_amdgcn_sched_barrier(0);

    const int bufs = (kt & 3) * 4096;
    const short* As = &LDS[bufs + (wr * 32 + lr) * 32 + kq * 8];
    const short* Bs = &LDS[bufs + 2048 + (wc * 32 + lr) * 32 + kq * 8];
    bfrag a0 = *(const bfrag*)&As[0];
    bfrag a1 = *(const bfrag*)&As[512];
    bfrag b0 = *(const bfrag*)&Bs[0];
    bfrag b1 = *(const bfrag*)&Bs[512];
    if (kt + 3 < NKT) MSTAGE(kt + 3);
    asm volatile("" ::: "memory");
    acc[0][0] = __builtin_amdgcn_mfma_f32_16x16x32_bf16(b0, a0, acc[0][0], 0, 0, 0);
    acc[0][1] = __builtin_amdgcn_mfma_f32_16x16x32_bf16(b1, a0, acc[0][1], 0, 0, 0);
    acc[1][0] = __builtin_amdgcn_mfma_f32_16x16x32_bf16(b0, a1, acc[1][0], 0, 0, 0);
    acc[1][1] = __builtin_amdgcn_mfma_f32_16x16x32_bf16(b1, a1, acc[1][1], 0, 0, 0);
  }

#pragma unroll
  for (int m = 0; m < 2; ++m)
#pragma unroll
    for (int n = 0; n < 2; ++n) {
      int gr = m0 + wr * 32 + m * 16 + lr;
      int jb = j0 + wc * 32 + n * 16 + kq * 4;
      int e  = jb >> 4;
      float w = wdense[(size_t)gr * NE + e];
      s16x4 o;
#pragma unroll
      for (int q = 0; q < 4; ++q) o[q] = f2bf(acc[m][n][q] * w);
      *(s16x4*)&XbW[(size_t)gr * KX + 4096 + jb] = o;
    }
#undef MSTAGE
}

// ---------------------------------------------------------------- main GEMM v4 (4 fine phases)
// 256x256 tile, BK=32, 8 waves (2Mx4N), ring-4 LDS, coalesced+xor-swizzled
// staging (0 conflicts), ring-4 counted vmcnt(8) residency (R3-proven).
// R6: K-tile split into 4 fine phases of 8 MFMAs each with just-in-time
// ds_reads + per-phase barrier + setprio — creates the anti-phase wave
// stagger (one wave of a SIMD issues LDS reads while its mate MFMAs) that
// the coarse 2-phase lockstep lacked (measured sum-serialization at 53%).
// Quadrant order Q00->Q10->Q11->Q01: no frag reload, peak 12 live frags.
__global__ __launch_bounds__(512, 2)
void moe_k_main8(const short* __restrict__ Xb, const short* __restrict__ Wb,
                 const int* __restrict__ flag, void* __restrict__ outp) {
  __shared__ __align__(16) short LDS[65536];  // 128 KiB: ring-4 x (A 16KB + B 16KB)
  const int t = threadIdx.x;
  const int l = t & 63;
  const int wv = t >> 6;
  const int wr = wv >> 2;
  const int wc = wv & 3;
  const int lr = l & 15;
  const int kq = l >> 4;

  int wg = blockIdx.x;
  int swz = (wg & 7) * 64 + (wg >> 3);
  const int tm = (swz >> 4) * 256;
  const int tn = (swz & 15) * 256;

  ffrag acc[8][4];
#pragma unroll
  for (int i = 0; i < 8; ++i)
#pragma unroll
    for (int j = 0; j < 4; ++j)
#pragma unroll
      for (int q = 0; q < 4; ++q) acc[i][j][q] = 0.f;

  // staging: chunk c -> row = c>>2, slot s = c&3, global kc = s ^ ((row>>1)&3)
  // split into 4 single-load macros (1 per phase; issue order A1,A2,B1,B2)
#define STAGE_ONE(kt_, base_, src_, half_)                                     \
  do {                                                                         \
    int _k0 = (kt_) * 32, _b = ((kt_) & 3) * 16384 + (base_);                  \
    int _c = (half_) * 512 + t;                                                \
    int _r = _c >> 2;                                                          \
    int _kc = (_c & 3) ^ ((_r >> 1) & 3);                                      \
    GLOAD16(&src_[(size_t)((base_ ? tn : tm) + _r) * KX + _k0 + _kc * 8],      \
            &LDS[_b + _c * 8]);                                                \
  } while (0)
#define STAGE_A1(kt_) STAGE_ONE(kt_, 0,    Xb, 0)
#define STAGE_A2(kt_) STAGE_ONE(kt_, 0,    Xb, 1)
#define STAGE_B1(kt_) STAGE_ONE(kt_, 8192, Wb, 0)
#define STAGE_B2(kt_) STAGE_ONE(kt_, 8192, Wb, 1)

  STAGE_A1(0); STAGE_A2(0); STAGE_B1(0); STAGE_B2(0);
  STAGE_A1(1); STAGE_A2(1); STAGE_B1(1); STAGE_B2(1);
  STAGE_A1(2); STAGE_A2(2); STAGE_B1(2); STAGE_B2(2);

  constexpr int NKT = KX / 32;  // 132

  const int kx = kq ^ ((lr >> 1) & 3);
  const int aofs = (wr * 128 + lr) * 32 + kx * 8;
  const int bofs = 8192 + (wc * 64 + lr) * 32 + kx * 8;

#define MFMA1(m_, n_, av_, bv_)                                                \
  acc[m_][n_] = __builtin_amdgcn_mfma_f32_16x16x32_bf16(bv_, av_, acc[m_][n_], 0, 0, 0);

  for (int kt = 0; kt < NKT; ++kt) {
    // ring-4 residency: tiles kt+1, kt+2 stay in flight (4 loads each)
    if (kt + 2 < NKT)      asm volatile("s_waitcnt vmcnt(8)" ::: "memory");
    else if (kt + 1 < NKT) asm volatile("s_waitcnt vmcnt(4)" ::: "memory");
    else                   asm volatile("s_waitcnt vmcnt(0)" ::: "memory");
    __builtin_amdgcn_s_barrier();
    __builtin_amdgcn_sched_barrier(0);

    const int bufs = (kt & 3) * 16384;
    const short* Ab = &LDS[bufs + aofs];
    const short* Bb = &LDS[bufs + bofs];

    // ---- P1: Q00 (m0-3 x n0-1)
    bfrag b0 = *(const bfrag*)&Bb[0];
    bfrag b1 = *(const bfrag*)&Bb[512];
    bfrag a0 = *(const bfrag*)&Ab[0];
    bfrag a1 = *(const bfrag*)&Ab[512];
    bfrag a2 = *(const bfrag*)&Ab[1024];
    bfrag a3 = *(const bfrag*)&Ab[1536];
    if (kt + 3 < NKT) STAGE_A1(kt + 3);
    __builtin_amdgcn_s_barrier();
    asm volatile("s_waitcnt lgkmcnt(0)" ::: "memory");
    __builtin_amdgcn_sched_barrier(0);
    __builtin_amdgcn_s_setprio(1);
    MFMA1(0, 0, a0, b0) MFMA1(0, 1, a0, b1)
    MFMA1(1, 0, a1, b0) MFMA1(1, 1, a1, b1)
    MFMA1(2, 0, a2, b0) MFMA1(2, 1, a2, b1)
    MFMA1(3, 0, a3, b0) MFMA1(3, 1, a3, b1)
    __builtin_amdgcn_s_setprio(0);
    __builtin_amdgcn_sched_barrier(0);

    // ---- P2: Q10 (m4-7 x n0-1)
    bfrag a4 = *(const bfrag*)&Ab[2048];
    bfrag a5 = *(const bfrag*)&Ab[2560];
    bfrag a6 = *(const bfrag*)&Ab[3072];
    bfrag a7 = *(const bfrag*)&Ab[3584];
    if (kt + 3 < NKT) STAGE_A2(kt + 3);
    __builtin_amdgcn_s_barrier();
    asm volatile("s_waitcnt lgkmcnt(0)" ::: "memory");
    __builtin_amdgcn_sched_barrier(0);
    __builtin_amdgcn_s_setprio(1);
    MFMA1(4, 0, a4, b0) MFMA1(4, 1, a4, b1)
    MFMA1(5, 0, a5, b0) MFMA1(5, 1, a5, b1)
    MFMA1(6, 0, a6, b0) MFMA1(6, 1, a6, b1)
    MFMA1(7, 0, a7, b0) MFMA1(7, 1, a7, b1)
    __builtin_amdgcn_s_setprio(0);
    __builtin_amdgcn_sched_barrier(0);

    // ---- P3: Q11 (m4-7 x n2-3)
    bfrag b2 = *(const bfrag*)&Bb[1024];
    bfrag b3 = *(const bfrag*)&Bb[1536];
    if (kt + 3 < NKT) STAGE_B1(kt + 3);
    __builtin_amdgcn_s_barrier();
    asm volatile("s_waitcnt lgkmcnt(0)" ::: "memory");
    __builtin_amdgcn_sched_barrier(0);
    __builtin_amdgcn_s_setprio(1);
    MFMA1(4, 2, a4, b2) MFMA1(4, 3, a4, b3)
    MFMA1(5, 2, a5, b2) MFMA1(5, 3, a5, b3)
    MFMA1(6, 2, a6, b2) MFMA1(6, 3, a6, b3)
    MFMA1(7, 2, a7, b2) MFMA1(7, 3, a7, b3)
    __builtin_amdgcn_s_setprio(0);
    __builtin_amdgcn_sched_barrier(0);

    // ---- P4: Q01 (m0-3 x n2-3) — operands held from P1/P3, no reads
    if (kt + 3 < NKT) STAGE_B2(kt + 3);
    __builtin_amdgcn_s_setprio(1);
    MFMA1(0, 2, a0, b2) MFMA1(0, 3, a0, b3)
    MFMA1(1, 2, a1, b2) MFMA1(1, 3, a1, b3)
    MFMA1(2, 2, a2, b2) MFMA1(2, 3, a2, b3)
    MFMA1(3, 2, a3, b2) MFMA1(3, 3, a3, b3)
    __builtin_amdgcn_s_setprio(0);
    __builtin_amdgcn_sched_barrier(0);
  }

  const bool bf = flag[0] != 0;
  float* of = (float*)outp;
  unsigned short* oh = (unsigned short*)outp;
#pragma unroll
  for (int m = 0; m < 8; ++m)
#pragma unroll
    for (int n = 0; n < 4; ++n) {
      int gr = tm + wr * 128 + m * 16 + lr;
      int gc = tn + wc * 64 + n * 16 + kq * 4;
      if (!bf) {
        *(f32x4*)&of[(size_t)gr * D + gc] = acc[m][n];
      } else {
        s16x4 o;
#pragma unroll
        for (int q = 0; q < 4; ++q) o[q] = f2bf(acc[m][n][q]);
        *(s16x4*)&oh[(size_t)gr * D + gc] = o;
      }
    }
#undef STAGE_ONE
#undef STAGE_A1
#undef STAGE_A2
#undef STAGE_B1
#undef STAGE_B2
#undef MFMA1
}

// ---------------------------------------------------------------- host
extern "C" void kernel_launch(void* const* d_in, const int* in_sizes, int n_in,
                              void* d_out, int out_size, void* d_ws, size_t ws_size,
                              hipStream_t stream) {
  const void* x  = d_in[0];
  const void* bw = d_in[1];
  const void* rw = d_in[2];
  const void* lA = d_in[3];
  const void* lB = d_in[4];

  char* ws = (char*)d_ws;
  const size_t XB_BYTES  = (size_t)NT * KX * 2;
  const size_t WB_BYTES  = (size_t)D * KX * 2;
  const size_t ABT_BYTES = (size_t)KE * D * 2;
  const size_t WD_BYTES  = (size_t)NT * NE * 4;
  const size_t NEED = 256 + XB_BYTES + WB_BYTES + ABT_BYTES + WD_BYTES;
  if (ws_size < NEED) return;

  int*   flag   = (int*)ws;
  short* Xb     = (short*)(ws + 256);
  short* Wb     = (short*)(ws + 256 + XB_BYTES);
  short* Abt    = (short*)(ws + 256 + XB_BYTES + WB_BYTES);
  float* wdense = (float*)(ws + 256 + XB_BYTES + WB_BYTES + ABT_BYTES);

  hipLaunchKernelGGL(moe_k_detect, dim3(1), dim3(64), 0, stream,
                     (const unsigned*)x, flag);
  hipLaunchKernelGGL(moe_k_prep_xr, dim3(10384), dim3(256), 0, stream,
                     bw, lA, lB, x, rw, flag, Wb, Abt, Xb, wdense);
  hipLaunchKernelGGL(moe_k_mid2, dim3(256), dim3(256), 0, stream,
                     Xb, Abt, wdense, Xb);
  hipLaunchKernelGGL(moe_k_main8, dim3(512), dim3(512), 0, stream,
                     Xb, Wb, flag, d_out);
}